// Round 1
// baseline (280.343 us; speedup 1.0000x reference)
//
#include <hip/hip_runtime.h>
#include <stdint.h>

#define T_SEQ 4096
#define NBATCH 8
#define CEMB 768
#define HS 64

typedef __attribute__((ext_vector_type(8))) short bf16x8;
typedef __attribute__((ext_vector_type(16))) float f32x16;

__device__ __forceinline__ short f2bf(float f) {
    uint32_t u = __builtin_bit_cast(uint32_t, f);
    u += 0x7FFFu + ((u >> 16) & 1u);     // RNE
    return (short)(u >> 16);
}

// 768^-0.5 * log2(e): fold attention scale AND exp->exp2 conversion into Q
#define QSCALE (0.036084391824351615f * 1.4426950408889634f)

// ---------------- prep: W (fp32 [768][64] x3) -> bf16 MFMA B-fragment layout ----------------
// wtf[((ct*48 + kc)*64 + lane)*8 + j] = Wcat[k][n], n = ct*32+(lane&31), k = kc*16+(lane>>5)*8+j
__global__ __launch_bounds__(256) void prep_wt(const float* __restrict__ Wq,
                                               const float* __restrict__ Wk,
                                               const float* __restrict__ Wv,
                                               short* __restrict__ wtf) {
    int gid  = blockIdx.x * 256 + threadIdx.x;   // 0 .. 147455
    int j    = gid & 7;
    int lane = (gid >> 3) & 63;
    int kc   = (gid >> 9) % 48;
    int ct   = gid / (48 * 512);                 // 0..5
    int n = ct * 32 + (lane & 31);
    int k = kc * 16 + (lane >> 5) * 8 + j;
    const float* W = (n < 64) ? Wq : ((n < 128) ? Wk : Wv);
    wtf[gid] = f2bf(W[k * 64 + (n & 63)]);
}

// ---------------- fused QKV projection ----------------
// grid 512 x 128 threads (2 waves); M-tile 64 rows; N = 192 (q|k|v); K = 768
__global__ __launch_bounds__(128) void qkv_proj(const float* __restrict__ x,
        const float* __restrict__ bq, const float* __restrict__ bk, const float* __restrict__ bv,
        const short* __restrict__ wtf,
        short* __restrict__ qo, short* __restrict__ ko, short* __restrict__ vto) {
    __shared__ short Alds[64 * 72];   // [row][k] pitch 72 (pad)
    __shared__ short Vtr[64 * 72];    // [vcol][row] transpose staging, pitch 72

    const int tid  = threadIdx.x;
    const int wave = tid >> 6, lane = tid & 63;
    const int l31  = lane & 31, lhi = lane >> 5;
    const int rowbase = blockIdx.x * 64;

    f32x16 acc[6] = {};

    for (int kt = 0; kt < 12; ++kt) {            // BK = 64
        {   // stage 64x64 fp32 -> bf16 into LDS (coalesced full-line reads)
            const int r = tid >> 1, h = tid & 1;
            const float4* src = (const float4*)(x + (long)(rowbase + r) * CEMB + kt * 64 + h * 32);
            short* dst = &Alds[r * 72 + h * 32];
            #pragma unroll
            for (int i = 0; i < 4; ++i) {
                float4 a = src[2 * i], c = src[2 * i + 1];
                bf16x8 w;
                w[0] = f2bf(a.x); w[1] = f2bf(a.y); w[2] = f2bf(a.z); w[3] = f2bf(a.w);
                w[4] = f2bf(c.x); w[5] = f2bf(c.y); w[6] = f2bf(c.z); w[7] = f2bf(c.w);
                *(bf16x8*)(dst + i * 8) = w;
            }
        }
        __syncthreads();
        #pragma unroll
        for (int kc = 0; kc < 4; ++kc) {
            bf16x8 af = *(const bf16x8*)&Alds[(wave * 32 + l31) * 72 + kc * 16 + lhi * 8];
            #pragma unroll
            for (int ct = 0; ct < 6; ++ct) {
                bf16x8 wf = *(const bf16x8*)&wtf[((ct * 48 + kt * 4 + kc) * 64 + lane) * 8];
                acc[ct] = __builtin_amdgcn_mfma_f32_32x32x16_bf16(af, wf, acc[ct], 0, 0, 0);
            }
        }
        __syncthreads();
    }

    // epilogue.  C/D: col = ct*32 + (lane&31), row = (r&3)+8*(r>>2)+4*(lane>>5)+wave*32
    #pragma unroll
    for (int ct = 0; ct < 2; ++ct) {             // q: pre-scaled by QSCALE (scale after bias!)
        float bb = bq[ct * 32 + l31];
        #pragma unroll
        for (int r = 0; r < 16; ++r) {
            int row = (r & 3) + 8 * (r >> 2) + 4 * lhi + wave * 32;
            qo[(rowbase + row) * HS + ct * 32 + l31] = f2bf((acc[ct][r] + bb) * QSCALE);
        }
    }
    #pragma unroll
    for (int ct = 2; ct < 4; ++ct) {             // k
        float bb = bk[(ct - 2) * 32 + l31];
        #pragma unroll
        for (int r = 0; r < 16; ++r) {
            int row = (r & 3) + 8 * (r >> 2) + 4 * lhi + wave * 32;
            ko[(rowbase + row) * HS + (ct - 2) * 32 + l31] = f2bf(acc[ct][r] + bb);
        }
    }
    #pragma unroll
    for (int ct = 4; ct < 6; ++ct) {             // v -> transpose via LDS
        float bb = bv[(ct - 4) * 32 + l31];
        #pragma unroll
        for (int r = 0; r < 16; ++r) {
            int row = (r & 3) + 8 * (r >> 2) + 4 * lhi + wave * 32;
            Vtr[((ct - 4) * 32 + l31) * 72 + row] = f2bf(acc[ct][r] + bb);
        }
    }
    __syncthreads();
    {   // write v transposed: vto[b][h][t], coalesced along t
        const int vcol = tid >> 1, h = tid & 1;
        const int b = rowbase >> 12;
        const int t0 = rowbase & 4095;
        short* dst = vto + ((long)b * HS + vcol) * T_SEQ + t0 + h * 32;
        #pragma unroll
        for (int i = 0; i < 4; ++i)
            *(bf16x8*)(dst + i * 8) = *(const bf16x8*)&Vtr[vcol * 72 + h * 32 + i * 8];
    }
}

// ---------------- fused attention (no-max softmax, flash-style K/V tiling) ----------------
// grid 256 x 256 threads (4 waves x 32 q-rows); BQ=128, BKt=128
__global__ __launch_bounds__(256) void attn(const short* __restrict__ qm,
        const short* __restrict__ km, const short* __restrict__ vtm,
        float* __restrict__ out) {
    __shared__ short Klds[128 * 72];     // [key][h]   pitch 72  (18.4 KB)
    __shared__ short Vlds[64 * 136];     // [h][key]   pitch 136 (17.4 KB)
    __shared__ short Plds[4][32 * 72];   // per-wave [qrow][key-half] pitch 72 (18.4 KB)

    const int tid  = threadIdx.x;
    const int wave = tid >> 6, lane = tid & 63;
    const int l31  = lane & 31, lhi = lane >> 5;
    const int b = blockIdx.x & 7, qt = blockIdx.x >> 3;  // batch->XCD swizzle for K/V L2 locality

    const short* qb = qm + ((long)b * T_SEQ + qt * 128) * HS;
    const short* kb = km + (long)b * T_SEQ * HS;
    const short* vb = vtm + (long)b * HS * T_SEQ;

    bf16x8 qf[4];                                   // Q fragments live in registers
    #pragma unroll
    for (int kc = 0; kc < 4; ++kc)
        qf[kc] = *(const bf16x8*)&qb[(wave * 32 + l31) * HS + kc * 16 + lhi * 8];

    bf16x8 ones;
    #pragma unroll
    for (int j = 0; j < 8; ++j) ones[j] = (short)0x3F80;   // bf16 1.0

    f32x16 oacc[2] = {};
    f32x16 lacc = {};
    short* pw = &Plds[wave][0];

    for (int kt = 0; kt < 32; ++kt) {
        const int kk0 = kt * 128;
        {   // stage K tile [128][64]
            const int r = tid >> 1, h = tid & 1;
            const bf16x8* src = (const bf16x8*)&kb[(kk0 + r) * HS + h * 32];
            short* dst = &Klds[r * 72 + h * 32];
            #pragma unroll
            for (int i = 0; i < 4; ++i) *(bf16x8*)(dst + i * 8) = src[i];
        }
        {   // stage V^T tile [64][128]
            const int hr = tid >> 2, c4 = tid & 3;
            const bf16x8* src = (const bf16x8*)&vb[hr * T_SEQ + kk0 + c4 * 32];
            short* dst = &Vlds[hr * 136 + c4 * 32];
            #pragma unroll
            for (int i = 0; i < 4; ++i) *(bf16x8*)(dst + i * 8) = src[i];
        }
        __syncthreads();

        // S = Q K^T (scale & log2e pre-folded into Q)
        f32x16 s[4];
        #pragma unroll
        for (int ct = 0; ct < 4; ++ct) {
            f32x16 z = {};
            #pragma unroll
            for (int kc = 0; kc < 4; ++kc) {
                bf16x8 kf = *(const bf16x8*)&Klds[(ct * 32 + l31) * 72 + kc * 16 + lhi * 8];
                z = __builtin_amdgcn_mfma_f32_32x32x16_bf16(qf[kc], kf, z, 0, 0, 0);
            }
            s[ct] = z;
        }

        // P = exp2(S), wave-private LDS round-trip (two 64-key halves), PV + rowsum MFMA
        #pragma unroll
        for (int half = 0; half < 2; ++half) {
            #pragma unroll
            for (int ct2 = 0; ct2 < 2; ++ct2) {
                const int ct = half * 2 + ct2;
                #pragma unroll
                for (int r = 0; r < 16; ++r) {
                    const int row = (r & 3) + 8 * (r >> 2) + 4 * lhi;
                    pw[row * 72 + ct2 * 32 + l31] = f2bf(__builtin_amdgcn_exp2f(s[ct][r]));
                }
            }
            #pragma unroll
            for (int kc2 = 0; kc2 < 4; ++kc2) {
                bf16x8 pf = *(const bf16x8*)&pw[l31 * 72 + kc2 * 16 + lhi * 8];
                lacc = __builtin_amdgcn_mfma_f32_32x32x16_bf16(pf, ones, lacc, 0, 0, 0);
                #pragma unroll
                for (int ht = 0; ht < 2; ++ht) {
                    bf16x8 vf = *(const bf16x8*)&Vlds[(ht * 32 + l31) * 136 + half * 64 + kc2 * 16 + lhi * 8];
                    oacc[ht] = __builtin_amdgcn_mfma_f32_32x32x16_bf16(pf, vf, oacc[ht], 0, 0, 0);
                }
            }
        }
        __syncthreads();
    }

    // epilogue: out[b][t][h] = O / l   (l shares the C/D row layout with O -> elementwise)
    float* ob = out + ((long)b * T_SEQ + qt * 128) * HS;
    #pragma unroll
    for (int ht = 0; ht < 2; ++ht) {
        #pragma unroll
        for (int r = 0; r < 16; ++r) {
            const int row = (r & 3) + 8 * (r >> 2) + 4 * lhi + wave * 32;
            ob[row * HS + ht * 32 + l31] = oacc[ht][r] / lacc[r];
        }
    }
}

extern "C" void kernel_launch(void* const* d_in, const int* in_sizes, int n_in,
                              void* d_out, int out_size, void* d_ws, size_t ws_size,
                              hipStream_t stream) {
    const float* x  = (const float*)d_in[0];
    const float* Wq = (const float*)d_in[1];
    const float* bq = (const float*)d_in[2];
    const float* Wk = (const float*)d_in[3];
    const float* bk = (const float*)d_in[4];
    const float* Wv = (const float*)d_in[5];
    const float* bv = (const float*)d_in[6];
    float* out = (float*)d_out;

    char* ws = (char*)d_ws;
    short* qo  = (short*)(ws);              // 32768*64 bf16, pre-scaled q
    short* ko  = (short*)(ws + 4194304);    // 32768*64 bf16
    short* vto = (short*)(ws + 8388608);    // [8][64][4096] bf16 (v transposed)
    short* wtf = (short*)(ws + 12582912);   // 768*192 bf16 fragment-ordered W

    prep_wt<<<576, 256, 0, stream>>>(Wq, Wk, Wv, wtf);
    qkv_proj<<<512, 128, 0, stream>>>(x, bq, bk, bv, wtf, qo, ko, vto);
    attn<<<256, 256, 0, stream>>>(qo, ko, vto, out);
}

// Round 2
// 227.631 us; speedup vs baseline: 1.2316x; 1.2316x over previous
//
#include <hip/hip_runtime.h>
#include <stdint.h>

#define T_SEQ 4096
#define CEMB 768
#define HS 64

typedef __attribute__((ext_vector_type(8))) short bf16x8;
typedef __attribute__((ext_vector_type(16))) float f32x16;

__device__ __forceinline__ short bfru(float f) {   // round-half-up to bf16 (2 ops)
    uint32_t u = __builtin_bit_cast(uint32_t, f);
    return (short)((u + 0x8000u) >> 16);
}
__device__ __forceinline__ short bftr(float f) {   // truncate to bf16 (bias cancels in O/l)
    return (short)(__builtin_bit_cast(uint32_t, f) >> 16);
}

// 768^-0.5 * log2(e): fold attention scale AND exp->exp2 conversion into Q
#define QSCALE (0.036084391824351615f * 1.4426950408889634f)

// ---------------- prep: W -> bf16 MFMA B-fragment layout (coalesced) ----------------
// wtf[((ct*48 + kq)*64 + lane)*8 + j] = Wcat[k][n], n = ct*32+(lane&31), k = kq*16+(lane>>5)*8+j
// grid = 288 blocks (one per (ct,kq)), 256 threads.
__global__ __launch_bounds__(256) void prep_wt(const float* __restrict__ Wq,
                                               const float* __restrict__ Wk,
                                               const float* __restrict__ Wv,
                                               short* __restrict__ wtf) {
    const int p = blockIdx.x;                 // ct*48 + kq
    const int ct = p / 48, kq = p % 48;
    const int tid = threadIdx.x;
    const int lane = tid & 63, jp = tid >> 6; // jp: 0..3 (j-pair)
    const int l31 = lane & 31, lhi = lane >> 5;
    const int k = kq * 16 + lhi * 8 + jp * 2;
    const int nn = ct * 32 + l31;
    const float* W = nn < 64 ? Wq : (nn < 128 ? Wk : Wv);
    const int col = nn & 63;
    uint32_t lo = (uint16_t)bfru(W[k * 64 + col]);        // lanes sweep col -> coalesced
    uint32_t hi = (uint16_t)bfru(W[(k + 1) * 64 + col]);
    *(uint32_t*)&wtf[(p * 64 + lane) * 8 + jp * 2] = lo | (hi << 16);
}

// ---------------- fused QKV projection ----------------
// grid 512 x 256 threads (4 waves). BM=64. ct-split: waves {0,1} -> ct 0..2, waves {2,3} -> ct 3..5.
__global__ __launch_bounds__(256) void qkv_proj(const float* __restrict__ x,
        const float* __restrict__ bq, const float* __restrict__ bk, const float* __restrict__ bv,
        const short* __restrict__ wtf,
        short* __restrict__ qo, short* __restrict__ ko, short* __restrict__ vto) {
    __shared__ short S[64 * 72];   // A tile [row][k] pitch 72; reused for V transpose in epilogue

    const int tid  = threadIdx.x;
    const int wave = tid >> 6, lane = tid & 63;
    const int l31  = lane & 31, lhi = lane >> 5;
    const int rg   = wave & 1;                 // row group (32 rows each)
    const int ctb  = (wave >> 1) * 3;          // ct base: 0 or 3
    const int rowbase = blockIdx.x * 64;

    f32x16 acc[3];                             // bias folded into accumulator init
    #pragma unroll
    for (int c = 0; c < 3; ++c) {
        const int ct = ctb + c, nn = ct * 32 + l31;
        const float bb = nn < 64 ? bq[nn] : (nn < 128 ? bk[nn - 64] : bv[nn - 128]);
        #pragma unroll
        for (int r = 0; r < 16; ++r) acc[c][r] = bb;
    }

    const int sr = tid >> 2, sseg = (tid & 3) * 16;      // staging: 64 rows x 4 segs of 16 floats
    for (int kt = 0; kt < 12; ++kt) {
        const float4* src = (const float4*)(x + (long)(rowbase + sr) * CEMB + kt * 64 + sseg);
        float4 f0 = src[0], f1 = src[1], f2 = src[2], f3 = src[3];
        bf16x8 w0, w1;
        w0[0]=bfru(f0.x); w0[1]=bfru(f0.y); w0[2]=bfru(f0.z); w0[3]=bfru(f0.w);
        w0[4]=bfru(f1.x); w0[5]=bfru(f1.y); w0[6]=bfru(f1.z); w0[7]=bfru(f1.w);
        w1[0]=bfru(f2.x); w1[1]=bfru(f2.y); w1[2]=bfru(f2.z); w1[3]=bfru(f2.w);
        w1[4]=bfru(f3.x); w1[5]=bfru(f3.y); w1[6]=bfru(f3.z); w1[7]=bfru(f3.w);
        *(bf16x8*)&S[sr * 72 + sseg]     = w0;
        *(bf16x8*)&S[sr * 72 + sseg + 8] = w1;
        __syncthreads();
        #pragma unroll
        for (int kc = 0; kc < 4; ++kc) {
            bf16x8 af = *(const bf16x8*)&S[(rg * 32 + l31) * 72 + kc * 16 + lhi * 8];
            #pragma unroll
            for (int c = 0; c < 3; ++c) {
                bf16x8 wf = *(const bf16x8*)&wtf[((ctb + c) * 48 + kt * 4 + kc) * 512 + lane * 8];
                acc[c] = __builtin_amdgcn_mfma_f32_32x32x16_bf16(af, wf, acc[c], 0, 0, 0);
            }
        }
        __syncthreads();
    }

    // epilogue.  C/D: col = l31 (+32*subtile), row = (r&3)+8*(r>>2)+4*lhi (+32*rg)
    #pragma unroll
    for (int c = 0; c < 3; ++c) {
        const int ct = ctb + c;
        if (ct < 2) {
            #pragma unroll
            for (int r = 0; r < 16; ++r) {
                const int row = rg * 32 + (r & 3) + 8 * (r >> 2) + 4 * lhi;
                qo[(long)(rowbase + row) * HS + ct * 32 + l31] = bfru(acc[c][r] * QSCALE);
            }
        } else if (ct < 4) {
            #pragma unroll
            for (int r = 0; r < 16; ++r) {
                const int row = rg * 32 + (r & 3) + 8 * (r >> 2) + 4 * lhi;
                ko[(long)(rowbase + row) * HS + (ct - 2) * 32 + l31] = bfru(acc[c][r]);
            }
        } else {
            #pragma unroll
            for (int r = 0; r < 16; ++r) {
                const int row = rg * 32 + (r & 3) + 8 * (r >> 2) + 4 * lhi;
                S[((ct - 4) * 32 + l31) * 72 + row] = bfru(acc[c][r]);   // V transpose staging
            }
        }
    }
    __syncthreads();
    if (tid < 128) {     // write v transposed: vto[b][h][t], coalesced along t
        const int vcol = tid >> 1, hh = tid & 1;
        const int b = rowbase >> 12, t0 = rowbase & 4095;
        short* dst = vto + ((long)b * HS + vcol) * T_SEQ + t0 + hh * 32;
        #pragma unroll
        for (int i = 0; i < 4; ++i)
            *(bf16x8*)(dst + i * 8) = *(const bf16x8*)&S[vcol * 72 + hh * 32 + i * 8];
    }
}

// ---------------- fused attention, key-split across blocks ----------------
// grid = 256*ks blocks x 256 threads (4 waves x 32 q-rows). BQ=128, BKt=64.
__global__ __launch_bounds__(256, 4) void attn(const short* __restrict__ qm,
        const short* __restrict__ km, const short* __restrict__ vtm,
        float* __restrict__ Op, float* __restrict__ lp, const int ks,
        float* __restrict__ outdirect) {
    __shared__ short Klds[64 * 72];      // [key][h]  9.2 KB
    __shared__ short Vlds[64 * 72];      // [h][key]  9.2 KB
    __shared__ short Plds[4][32 * 40];   // per-wave [qrow][key32] 10 KB  -> total 28 KB

    const int tid  = threadIdx.x;
    const int wave = tid >> 6, lane = tid & 63;
    const int l31  = lane & 31, lhi = lane >> 5;
    const int idx  = blockIdx.x;
    const int b = idx & 7, s = (idx >> 3) % ks, qt = idx / (8 * ks);
    const int slab = T_SEQ / ks, nkt = slab / 64;

    const short* qb = qm + ((long)b * T_SEQ + qt * 128) * HS;
    const short* kb = km + ((long)b * T_SEQ + s * slab) * HS;
    const short* vb = vtm + (long)b * HS * T_SEQ + s * slab;

    bf16x8 qf[4];
    #pragma unroll
    for (int kc = 0; kc < 4; ++kc)
        qf[kc] = *(const bf16x8*)&qb[(wave * 32 + l31) * HS + kc * 16 + lhi * 8];

    bf16x8 ones;
    #pragma unroll
    for (int j = 0; j < 8; ++j) ones[j] = (short)0x3F80;

    f32x16 oacc[2] = {};
    f32x16 lacc = {};
    short* pw = &Plds[wave][0];

    const int sr = tid >> 2, sc = (tid & 3) * 16;
    for (int kt = 0; kt < nkt; ++kt) {
        const int k0 = kt * 64;
        {   const short* p1 = &kb[(k0 + sr) * HS + sc];
            *(bf16x8*)&Klds[sr * 72 + sc]     = *(const bf16x8*)p1;
            *(bf16x8*)&Klds[sr * 72 + sc + 8] = *(const bf16x8*)(p1 + 8); }
        {   const short* p2 = &vb[sr * T_SEQ + k0 + sc];
            *(bf16x8*)&Vlds[sr * 72 + sc]     = *(const bf16x8*)p2;
            *(bf16x8*)&Vlds[sr * 72 + sc + 8] = *(const bf16x8*)(p2 + 8); }
        __syncthreads();

        #pragma unroll
        for (int ct = 0; ct < 2; ++ct) {          // 32-key subtiles
            f32x16 z = {};
            #pragma unroll
            for (int kc = 0; kc < 4; ++kc) {
                bf16x8 kf = *(const bf16x8*)&Klds[(ct * 32 + l31) * 72 + kc * 16 + lhi * 8];
                z = __builtin_amdgcn_mfma_f32_32x32x16_bf16(qf[kc], kf, z, 0, 0, 0);
            }
            #pragma unroll
            for (int r = 0; r < 16; ++r) {
                const int row = (r & 3) + 8 * (r >> 2) + 4 * lhi;
                pw[row * 40 + l31] = bftr(__builtin_amdgcn_exp2f(z[r]));
            }
            #pragma unroll
            for (int kc2 = 0; kc2 < 2; ++kc2) {
                bf16x8 pf = *(const bf16x8*)&pw[l31 * 40 + kc2 * 16 + lhi * 8];
                lacc = __builtin_amdgcn_mfma_f32_32x32x16_bf16(pf, ones, lacc, 0, 0, 0);
                #pragma unroll
                for (int ht = 0; ht < 2; ++ht) {
                    bf16x8 vf = *(const bf16x8*)&Vlds[(ht * 32 + l31) * 72 + ct * 32 + kc2 * 16 + lhi * 8];
                    oacc[ht] = __builtin_amdgcn_mfma_f32_32x32x16_bf16(pf, vf, oacc[ht], 0, 0, 0);
                }
            }
        }
        __syncthreads();
    }

    const long rowg = (long)b * T_SEQ + qt * 128 + wave * 32;
    if (outdirect) {            // ks==1 path: normalize in-kernel
        float* ob = outdirect + rowg * HS;
        #pragma unroll
        for (int ht = 0; ht < 2; ++ht)
            #pragma unroll
            for (int r = 0; r < 16; ++r) {
                const int row = (r & 3) + 8 * (r >> 2) + 4 * lhi;
                ob[row * HS + ht * 32 + l31] = oacc[ht][r] / lacc[r];
            }
    } else {
        float* op = Op + ((long)s * 32768 + rowg) * HS;
        #pragma unroll
        for (int ht = 0; ht < 2; ++ht)
            #pragma unroll
            for (int r = 0; r < 16; ++r) {
                const int row = (r & 3) + 8 * (r >> 2) + 4 * lhi;
                op[row * HS + ht * 32 + l31] = oacc[ht][r];
            }
        if (l31 == 0) {
            #pragma unroll
            for (int r = 0; r < 16; ++r)
                lp[(long)s * 32768 + rowg + (r & 3) + 8 * (r >> 2) + 4 * lhi] = lacc[r];
        }
    }
}

// ---------------- combine partials: out = sum_s O_s / sum_s l_s ----------------
__global__ __launch_bounds__(256) void combine(const float4* __restrict__ Op,
        const float* __restrict__ lp, float4* __restrict__ out, const int ks) {
    const int idx = blockIdx.x * 256 + threadIdx.x;   // 524288 = 32768 rows x 16 float4
    const int row = idx >> 4, h4 = idx & 15;
    float ox = 0.f, oy = 0.f, oz = 0.f, ow = 0.f, l = 0.f;
    for (int s = 0; s < ks; ++s) {
        float4 t = Op[(long)(s * 32768 + row) * 16 + h4];
        ox += t.x; oy += t.y; oz += t.z; ow += t.w;
        l += lp[s * 32768 + row];
    }
    const float inv = 1.0f / l;
    float4 o; o.x = ox * inv; o.y = oy * inv; o.z = oz * inv; o.w = ow * inv;
    out[(long)row * 16 + h4] = o;
}

extern "C" void kernel_launch(void* const* d_in, const int* in_sizes, int n_in,
                              void* d_out, int out_size, void* d_ws, size_t ws_size,
                              hipStream_t stream) {
    const float* x  = (const float*)d_in[0];
    const float* Wq = (const float*)d_in[1];
    const float* bq = (const float*)d_in[2];
    const float* Wk = (const float*)d_in[3];
    const float* bk = (const float*)d_in[4];
    const float* Wv = (const float*)d_in[5];
    const float* bv = (const float*)d_in[6];

    char* ws = (char*)d_ws;
    short* qo  = (short*)(ws);                     // 4 MB
    short* ko  = (short*)(ws + (4u << 20));        // 4 MB
    short* vto = (short*)(ws + (8u << 20));        // 4 MB  [b][h][t]
    short* wtf = (short*)(ws + (12u << 20));       // 288 KB
    const size_t opOff = 12582912u + 294912u;      // 12877824, 16B aligned
    float* Op = (float*)(ws + opOff);

    const size_t per_s = 8388608u + 131072u;       // O partial + l partial per split
    int ks = (ws_size >= opOff + 4 * per_s) ? 4
           : (ws_size >= opOff + 2 * per_s) ? 2 : 1;
    float* lp = (float*)(ws + opOff + (size_t)ks * 8388608u);

    prep_wt<<<288, 256, 0, stream>>>(Wq, Wk, Wv, wtf);
    qkv_proj<<<512, 256, 0, stream>>>(x, bq, bk, bv, wtf, qo, ko, vto);
    attn<<<256 * ks, 256, 0, stream>>>(qo, ko, vto, Op, lp, ks,
                                       ks == 1 ? (float*)d_out : nullptr);
    if (ks > 1)
        combine<<<2048, 256, 0, stream>>>((const float4*)Op, lp, (float4*)d_out, ks);
}